// Round 1
// baseline (326.178 us; speedup 1.0000x reference)
//
#include <hip/hip_runtime.h>

#define NBINS 512

// ws layout (floats): [0:512) = per-bin column sums, [512:768) = weighted-add accumulator slots
__global__ void init_ws_kernel(float* __restrict__ ws, int n) {
    int t = blockIdx.x * blockDim.x + threadIdx.x;
    if (t < n) ws[t] = 0.0f;
}

// One block per batch row b; wave w (of K=16) handles neighbor k=w.
// Each lane owns 8 contiguous bins (2x float4). Base row staged in LDS.
__global__ __launch_bounds__(1024) void main_kernel(
        const float* __restrict__ outputs,
        const float* __restrict__ y,
        const float* __restrict__ weights,
        float* __restrict__ out,          // d_out: [cost, diff, bnorm, booster(B)]
        float* __restrict__ accum,        // 256 slots
        int K) {
    __shared__ float4 sbase[NBINS / 4];   // 512 floats = 2 KB
    __shared__ float s_add[16];

    const int b = blockIdx.x;
    const int t = threadIdx.x;

    // Stage base row outputs[b, :] into LDS (128 float4 loads, coalesced)
    if (t < NBINS / 4)
        sbase[t] = ((const float4*)(outputs + (size_t)b * NBINS))[t];
    __syncthreads();

    const int w = t >> 6;
    const int lane = t & 63;

    // Gather neighbor row, per-lane max of 8 (base+gather) sums
    const int nn = (int)y[b * K + w];     // y >= 0, trunc == (int) cast
    const float4* rp = (const float4*)(outputs + (size_t)nn * NBINS);
    float4 g0 = rp[lane * 2];
    float4 g1 = rp[lane * 2 + 1];
    float4 b0 = sbase[lane * 2];
    float4 b1 = sbase[lane * 2 + 1];

    float m = fmaxf(fmaxf(fmaxf(g0.x + b0.x, g0.y + b0.y),
                          fmaxf(g0.z + b0.z, g0.w + b0.w)),
                    fmaxf(fmaxf(g1.x + b1.x, g1.y + b1.y),
                          fmaxf(g1.z + b1.z, g1.w + b1.w)));

    // Wave-wide max reduce (64 lanes)
    #pragma unroll
    for (int off = 32; off > 0; off >>= 1)
        m = fmaxf(m, __shfl_down(m, off, 64));

    if (lane == 0) s_add[w] = m;
    __syncthreads();

    if (t == 0) {
        float sum = 0.0f;
        #pragma unroll
        for (int i = 0; i < 16; ++i) sum += s_add[i];
        float mean = sum * (1.0f / 16.0f);
        float booster = fmaxf(0.5f, (2.0f - mean) * 0.5f);
        out[3 + b] = booster;
        // spread atomics over 256 slots to avoid same-address serialization
        atomicAdd(&accum[b & 255], weights[b] * sum);
    }
}

// Column sums over the first B rows of outputs. 64 blocks x 512 threads,
// each block handles a contiguous chunk of rows; coalesced (thread = bin).
__global__ void colsum_kernel(const float* __restrict__ outputs,
                              float* __restrict__ bcol,
                              int rows_per_block) {
    const int t = threadIdx.x;            // bin index, 0..511
    const int r0 = blockIdx.x * rows_per_block;
    float local = 0.0f;
    for (int r = 0; r < rows_per_block; ++r)
        local += outputs[(size_t)(r0 + r) * NBINS + t];
    atomicAdd(&bcol[t], local);
}

__global__ void final_kernel(const float* __restrict__ bcol,
                             const float* __restrict__ accum,
                             float* __restrict__ out,
                             float inv_count, float inv_target) {
    __shared__ float smax[NBINS];
    __shared__ float smin[NBINS];
    const int t = threadIdx.x;
    float v = bcol[t];
    smax[t] = v;
    smin[t] = v;
    __syncthreads();
    for (int s = NBINS / 2; s > 0; s >>= 1) {
        if (t < s) {
            smax[t] = fmaxf(smax[t], smax[t + s]);
            smin[t] = fminf(smin[t], smin[t + s]);
        }
        __syncthreads();
    }
    if (t == 0) {
        float acc = 0.0f;
        for (int i = 0; i < 256; ++i) acc += accum[i];
        float add_mean = acc * inv_count;
        float d = 2.0f - add_mean;
        float diff = d * d;
        float bn = (smax[0] - smin[0]) * inv_target;
        out[0] = bn + diff;
        out[1] = diff;
        out[2] = bn;
    }
}

extern "C" void kernel_launch(void* const* d_in, const int* in_sizes, int n_in,
                              void* d_out, int out_size, void* d_ws, size_t ws_size,
                              hipStream_t stream) {
    const float* outputs = (const float*)d_in[0];  // (N, 512)
    const float* y       = (const float*)d_in[1];  // (B, K) float-encoded indices
    const float* weights = (const float*)d_in[2];  // (B,)
    float* out = (float*)d_out;

    const int B = in_sizes[2];              // 8192
    const int K = in_sizes[1] / B;          // 16
    const int N = in_sizes[0] / NBINS;      // 100000

    float* ws    = (float*)d_ws;
    float* bcol  = ws;                      // 512 floats
    float* accum = ws + NBINS;              // 256 floats

    // ws is re-poisoned (0xAA) before every timed launch — zero it here.
    init_ws_kernel<<<1, 1024, 0, stream>>>(ws, NBINS + 256);

    main_kernel<<<B, K * 64, 0, stream>>>(outputs, y, weights, out, accum, K);

    const int rows_per_block = 128;         // 64 blocks cover B=8192 rows
    colsum_kernel<<<B / rows_per_block, NBINS, 0, stream>>>(outputs, bcol, rows_per_block);

    final_kernel<<<1, NBINS, 0, stream>>>(bcol, accum, out,
                                          1.0f / (float)(B * K),
                                          (float)NBINS / (float)N);
}